// Round 1
// baseline (43.752 us; speedup 1.0000x reference)
//
#include <hip/hip_runtime.h>
#include <math.h>

// ---- problem constants ----
#define NB    512   // batch
#define STATE 512
#define IMS   224
#define SBW   16
#define TSB   768   // 3*16*16
#define HGN   128
#define GN    256

// depth-1 (32->16) antialiased linear weights: taps at j = 2*o-1 + a
__device__ __forceinline__ void d1w(int o, float w[4]) {
    w[0] = 0.125f; w[1] = 0.375f; w[2] = 0.375f; w[3] = 0.125f;
    if (o == 0)  { w[0] = 0.f;      w[1] = 3.f/7.f; w[2] = 3.f/7.f; w[3] = 1.f/7.f; }
    if (o == 15) { w[0] = 1.f/7.f;  w[1] = 3.f/7.f; w[2] = 3.f/7.f; w[3] = 0.f; }
}
// depth-2 (64->16) weights: taps at j = 4*o-2 + a
__device__ __forceinline__ void d2w(int o, float w[8]) {
    const float s = 1.f/32.f;
    w[0]=1*s; w[1]=3*s; w[2]=5*s; w[3]=7*s; w[4]=7*s; w[5]=5*s; w[6]=3*s; w[7]=1*s;
    if (o == 0)  { const float t=1.f/28.f; w[0]=0.f; w[1]=0.f; w[2]=5*t; w[3]=7*t; w[4]=7*t; w[5]=5*t; w[6]=3*t; w[7]=1*t; }
    if (o == 15) { const float t=1.f/28.f; w[0]=1*t; w[1]=3*t; w[2]=5*t; w[3]=7*t; w[4]=7*t; w[5]=5*t; w[6]=0.f; w[7]=0.f; }
}

// Kernel A: per-sample loc + 64x64 window -> 3-depth glimpses
__global__ __launch_bounds__(256) void ka_loc_glimpse(
    const float* __restrict__ out_state,  // [512][512]
    const float* __restrict__ img,        // [512][224][224]
    const float* __restrict__ W_loc,      // [512][2]
    const float* __restrict__ b_loc,      // [2]
    float* __restrict__ gl,               // [512][768]
    float* __restrict__ loc_out)          // [512][2]
{
    const int b   = blockIdx.x;
    const int tid = threadIdx.x;
    __shared__ float win[64][64];
    __shared__ float red[4][2];
    __shared__ float s_loc[2];
    __shared__ int   s_li[2];

    // ---- loc = clip(output @ W_loc + b_loc) ----
    float a0 = 0.f, a1 = 0.f;
    const float* orow = out_state + (size_t)b * STATE;
    for (int k = tid; k < STATE; k += 256) {
        float x = orow[k];
        a0 += x * W_loc[k*2 + 0];
        a1 += x * W_loc[k*2 + 1];
    }
    for (int off = 32; off; off >>= 1) {
        a0 += __shfl_down(a0, off);
        a1 += __shfl_down(a1, off);
    }
    int wid = tid >> 6;
    if ((tid & 63) == 0) { red[wid][0] = a0; red[wid][1] = a1; }
    __syncthreads();
    if (tid == 0) {
        float l0 = red[0][0] + red[1][0] + red[2][0] + red[3][0] + b_loc[0];
        float l1 = red[0][1] + red[1][1] + red[2][1] + red[3][1] + b_loc[1];
        l0 = fminf(fmaxf(l0, -1.f), 1.f);
        l1 = fminf(fmaxf(l1, -1.f), 1.f);
        s_loc[0] = l0; s_loc[1] = l1;
        s_li[0] = (int)rintf((l0 + 1.f) * 0.5f * (float)IMS);
        s_li[1] = (int)rintf((l1 + 1.f) * 0.5f * (float)IMS);
        loc_out[b*2 + 0] = l0; loc_out[b*2 + 1] = l1;
    }
    __syncthreads();
    const int li = s_li[0], lj = s_li[1];

    // ---- load 64x64 window centered at (li, lj), zero outside image ----
    const float* im = img + (size_t)b * IMS * IMS;
    #pragma unroll
    for (int i = 0; i < 16; ++i) {
        int idx = tid + i * 256;
        int r = idx >> 6, c = idx & 63;
        int rr = li - 32 + r, cc = lj - 32 + c;
        float v = 0.f;
        if ((unsigned)rr < (unsigned)IMS && (unsigned)cc < (unsigned)IMS)
            v = im[rr * IMS + cc];
        win[r][c] = v;
    }
    __syncthreads();

    const int r = tid >> 4, c = tid & 15;
    float* glb = gl + (size_t)b * TSB;

    // depth 0: center 16x16 copy
    glb[tid] = win[24 + r][24 + c];

    // depth 1: 32->16, crop starts at win offset 16; taps j in [-1,32] all land in [15,48]
    {
        float wr[4], wc[4];
        d1w(r, wr); d1w(c, wc);
        int jr0 = 2*r - 1, jc0 = 2*c - 1;
        float acc = 0.f;
        #pragma unroll
        for (int a = 0; a < 4; ++a) {
            float rowsum = 0.f;
            #pragma unroll
            for (int bb = 0; bb < 4; ++bb)
                rowsum += wc[bb] * win[16 + jr0 + a][16 + jc0 + bb];
            acc += wr[a] * rowsum;
        }
        glb[256 + tid] = acc;
    }

    // depth 2: 64->16, full window; clamp indices (clamped taps have zero weight)
    {
        float wr[8], wc[8];
        d2w(r, wr); d2w(c, wc);
        int jr0 = 4*r - 2, jc0 = 4*c - 2;
        float acc = 0.f;
        #pragma unroll
        for (int a = 0; a < 8; ++a) {
            int jr = min(max(jr0 + a, 0), 63);
            float rowsum = 0.f;
            #pragma unroll
            for (int bb = 0; bb < 8; ++bb) {
                int jc = min(max(jc0 + bb, 0), 63);
                rowsum += wc[bb] * win[jr][jc];
            }
            acc += wr[a] * rowsum;
        }
        glb[512 + tid] = acc;
    }
}

// Kernel B1: hg = relu(glimpses @ W_hg + b_hg)   [512,768]x[768,128]
// 4 samples per block, one thread per (sample, col)
__global__ __launch_bounds__(512) void kb_hg(
    const float* __restrict__ gl,     // [512][768]
    const float* __restrict__ W_hg,   // [768][128]
    const float* __restrict__ b_hg,   // [128]
    float* __restrict__ hg)           // [512][128]
{
    const int col = threadIdx.x & 127;
    const int s   = threadIdx.x >> 7;          // 0..3
    const int b   = blockIdx.x * 4 + s;
    const float* g = gl + (size_t)b * TSB;
    float acc = b_hg[col];
    for (int k = 0; k < TSB; k += 4) {
        float4 gv = *(const float4*)(g + k);
        acc += gv.x * W_hg[(k+0)*HGN + col];
        acc += gv.y * W_hg[(k+1)*HGN + col];
        acc += gv.z * W_hg[(k+2)*HGN + col];
        acc += gv.w * W_hg[(k+3)*HGN + col];
    }
    hg[(size_t)b * HGN + col] = fmaxf(acc, 0.f);
}

// Kernel B2: hl = relu(loc @ W_hl + b_hl);  g = relu(hg@W_gs + hl@W_ls + b_gs + b_ls)
// 2 samples per block; hg/hl staged in LDS
__global__ __launch_bounds__(512) void kb_g(
    const float* __restrict__ hg,     // [512][128]
    const float* __restrict__ loc,    // [512][2]
    const float* __restrict__ W_hl,   // [2][128]
    const float* __restrict__ b_hl,   // [128]
    const float* __restrict__ W_gs,   // [128][256]
    const float* __restrict__ b_gs,   // [256]
    const float* __restrict__ W_ls,   // [128][256]
    const float* __restrict__ b_ls,   // [256]
    float* __restrict__ out)          // [512][256]
{
    __shared__ float s_hg[2][HGN];
    __shared__ float s_hl[2][HGN];
    const int t = threadIdx.x;
    const int n = t & 255;
    const int s = t >> 8;               // 0..1
    const int b = blockIdx.x * 2 + s;

    if (t < 256) {
        int ss = t >> 7, j = t & 127;
        s_hg[ss][j] = hg[(size_t)(blockIdx.x*2 + ss) * HGN + j];
    } else {
        int tt = t - 256, ss = tt >> 7, j = tt & 127;
        float l0 = loc[(blockIdx.x*2 + ss)*2 + 0];
        float l1 = loc[(blockIdx.x*2 + ss)*2 + 1];
        s_hl[ss][j] = fmaxf(l0 * W_hl[j] + l1 * W_hl[HGN + j] + b_hl[j], 0.f);
    }
    __syncthreads();

    float acc = b_gs[n] + b_ls[n];
    #pragma unroll 4
    for (int j = 0; j < HGN; ++j) {
        acc += s_hg[s][j] * W_gs[j*GN + n];
        acc += s_hl[s][j] * W_ls[j*GN + n];
    }
    out[(size_t)b * GN + n] = fmaxf(acc, 0.f);
}

extern "C" void kernel_launch(void* const* d_in, const int* in_sizes, int n_in,
                              void* d_out, int out_size, void* d_ws, size_t ws_size,
                              hipStream_t stream) {
    const float* out_state = (const float*)d_in[0];
    const float* img       = (const float*)d_in[1];
    const float* W_loc     = (const float*)d_in[2];
    const float* b_loc     = (const float*)d_in[3];
    const float* W_hg      = (const float*)d_in[4];
    const float* b_hg      = (const float*)d_in[5];
    const float* W_hl      = (const float*)d_in[6];
    const float* b_hl      = (const float*)d_in[7];
    const float* W_gs      = (const float*)d_in[8];
    const float* b_gs      = (const float*)d_in[9];
    const float* W_ls      = (const float*)d_in[10];
    const float* b_ls      = (const float*)d_in[11];
    float* out = (float*)d_out;

    char* ws = (char*)d_ws;
    float* gl  = (float*)(ws);                                   // 512*768 f32
    float* loc = (float*)(ws + (size_t)NB*TSB*4);                // 512*2 f32
    float* hg  = (float*)(ws + (size_t)NB*TSB*4 + 4096);         // 512*128 f32

    hipLaunchKernelGGL(ka_loc_glimpse, dim3(NB), dim3(256), 0, stream,
                       out_state, img, W_loc, b_loc, gl, loc);
    hipLaunchKernelGGL(kb_hg, dim3(NB/4), dim3(512), 0, stream,
                       gl, W_hg, b_hg, hg);
    hipLaunchKernelGGL(kb_g, dim3(NB/2), dim3(512), 0, stream,
                       hg, loc, W_hl, b_hl, W_gs, b_gs, W_ls, b_ls, out);
}

// Round 2
// 26.565 us; speedup vs baseline: 1.6470x; 1.6470x over previous
//
#include <hip/hip_runtime.h>
#include <math.h>

// ---- problem constants ----
#define NB    512   // batch
#define STATE 512
#define IMS   224
#define TSB   768   // 3*16*16
#define HGN   128
#define GN    256
#define WPITCH 65   // 64 + 1 pad (bank-conflict break)

// depth-1 (32->16) antialiased linear weights: taps at j = 2*o-1 + a
__device__ __forceinline__ void d1w(int o, float w[4]) {
    w[0] = 0.125f; w[1] = 0.375f; w[2] = 0.375f; w[3] = 0.125f;
    if (o == 0)  { w[0] = 0.f;      w[1] = 3.f/7.f; w[2] = 3.f/7.f; w[3] = 1.f/7.f; }
    if (o == 15) { w[0] = 1.f/7.f;  w[1] = 3.f/7.f; w[2] = 3.f/7.f; w[3] = 0.f; }
}
// depth-2 (64->16) weights: taps at j = 4*o-2 + a
__device__ __forceinline__ void d2w(int o, float w[8]) {
    const float s = 1.f/32.f;
    w[0]=1*s; w[1]=3*s; w[2]=5*s; w[3]=7*s; w[4]=7*s; w[5]=5*s; w[6]=3*s; w[7]=1*s;
    if (o == 0)  { const float t=1.f/28.f; w[0]=0.f; w[1]=0.f; w[2]=5*t; w[3]=7*t; w[4]=7*t; w[5]=5*t; w[6]=3*t; w[7]=1*t; }
    if (o == 15) { const float t=1.f/28.f; w[0]=1*t; w[1]=3*t; w[2]=5*t; w[3]=7*t; w[4]=7*t; w[5]=5*t; w[6]=0.f; w[7]=0.f; }
}

// Fully fused: loc -> glimpses -> hg -> hl -> g.  2 samples per block.
__global__ __launch_bounds__(512) void fused_attn(
    const float* __restrict__ out_state,  // [512][512]
    const float* __restrict__ img,        // [512][224][224]
    const float* __restrict__ W_loc, const float* __restrict__ b_loc,
    const float* __restrict__ W_hg,  const float* __restrict__ b_hg,
    const float* __restrict__ W_hl,  const float* __restrict__ b_hl,
    const float* __restrict__ W_gs,  const float* __restrict__ b_gs,
    const float* __restrict__ W_ls,  const float* __restrict__ b_ls,
    float* __restrict__ out)              // [512][256]
{
    __shared__ float win[2][64 * WPITCH];   // 33.3 KB
    __shared__ float gl[2][TSB];            // 6 KB
    __shared__ float s_hg[2][HGN];
    __shared__ float s_hl[2][HGN];
    __shared__ float part[2][HGN];
    __shared__ float red[8][2];
    __shared__ float s_loc[2][2];
    __shared__ int   s_li[2][2];

    const int t  = threadIdx.x;
    const int b0 = blockIdx.x * 2;

    // ---- phase 1: loc = clip(output @ W_loc + b_loc); waves 0-3 -> sample 0, 4-7 -> sample 1
    {
        int s = t >> 8, k = t & 255;
        const float* orow = out_state + (size_t)(b0 + s) * STATE;
        float x0 = orow[k], x1 = orow[k + 256];
        float a0 = x0 * W_loc[k*2]     + x1 * W_loc[(k+256)*2];
        float a1 = x0 * W_loc[k*2 + 1] + x1 * W_loc[(k+256)*2 + 1];
        for (int off = 32; off; off >>= 1) {
            a0 += __shfl_down(a0, off);
            a1 += __shfl_down(a1, off);
        }
        if ((t & 63) == 0) { red[t>>6][0] = a0; red[t>>6][1] = a1; }
    }
    __syncthreads();
    if ((t & 255) == 0) {
        int s = t >> 8;
        float l0 = red[4*s][0]+red[4*s+1][0]+red[4*s+2][0]+red[4*s+3][0] + b_loc[0];
        float l1 = red[4*s][1]+red[4*s+1][1]+red[4*s+2][1]+red[4*s+3][1] + b_loc[1];
        l0 = fminf(fmaxf(l0, -1.f), 1.f);
        l1 = fminf(fmaxf(l1, -1.f), 1.f);
        s_loc[s][0] = l0; s_loc[s][1] = l1;
        s_li[s][0] = (int)rintf((l0 + 1.f) * 0.5f * (float)IMS);
        s_li[s][1] = (int)rintf((l1 + 1.f) * 0.5f * (float)IMS);
    }
    __syncthreads();

    // ---- phase 2: 64x64 windows centered at loc, zero outside image
    #pragma unroll
    for (int i = 0; i < 16; ++i) {
        int idx = t + i * 512;
        int s = idx >> 12, rem = idx & 4095;
        int r = rem >> 6, c = rem & 63;
        int rr = s_li[s][0] - 32 + r, cc = s_li[s][1] - 32 + c;
        float v = 0.f;
        if ((unsigned)rr < (unsigned)IMS && (unsigned)cc < (unsigned)IMS)
            v = img[(size_t)(b0 + s) * IMS * IMS + rr * IMS + cc];
        win[s][r * WPITCH + c] = v;
    }
    __syncthreads();

    // ---- phase 3: 3-depth glimpses -> gl LDS
    {
        int s = t >> 8, p = t & 255, r = p >> 4, c = p & 15;
        const float* w = win[s];
        // depth 0
        gl[s][p] = w[(24 + r) * WPITCH + (24 + c)];
        // depth 1: crop offset 16; taps in [15,48]
        {
            float wr[4], wc[4];
            d1w(r, wr); d1w(c, wc);
            int jr0 = 16 + 2*r - 1, jc0 = 16 + 2*c - 1;
            float acc = 0.f;
            #pragma unroll
            for (int a = 0; a < 4; ++a) {
                float rowsum = 0.f;
                #pragma unroll
                for (int bb = 0; bb < 4; ++bb)
                    rowsum += wc[bb] * w[(jr0 + a) * WPITCH + (jc0 + bb)];
                acc += wr[a] * rowsum;
            }
            gl[s][256 + p] = acc;
        }
        // depth 2: full window, clamped taps have zero weight
        {
            float wr[8], wc[8];
            d2w(r, wr); d2w(c, wc);
            int jr0 = 4*r - 2, jc0 = 4*c - 2;
            float acc = 0.f;
            #pragma unroll
            for (int a = 0; a < 8; ++a) {
                int jr = min(max(jr0 + a, 0), 63);
                float rowsum = 0.f;
                #pragma unroll
                for (int bb = 0; bb < 8; ++bb) {
                    int jc = min(max(jc0 + bb, 0), 63);
                    rowsum += wc[bb] * w[jr * WPITCH + jc];
                }
                acc += wr[a] * rowsum;
            }
            gl[s][512 + p] = acc;
        }
    }
    __syncthreads();

    // ---- phase 4: hg = relu(gl @ W_hg + b_hg), split-k over 2 halves
    {
        int col = t & 127, s = (t >> 7) & 1, h = t >> 8;
        float acc = h ? 0.f : b_hg[col];
        const float* gp = gl[s] + h * 384;
        const float* wp = W_hg + (size_t)(h * 384) * HGN + col;
        #pragma unroll 4
        for (int k = 0; k < 384; ++k)
            acc += gp[k] * wp[(size_t)k * HGN];
        if (h) part[s][col] = acc;
        __syncthreads();
        if (!h) {
            s_hg[s][col] = fmaxf(acc + part[s][col], 0.f);
        } else {
            // phase 5: hl = relu(loc @ W_hl + b_hl) on the other half
            float l0 = s_loc[s][0], l1 = s_loc[s][1];
            s_hl[s][col] = fmaxf(l0 * W_hl[col] + l1 * W_hl[HGN + col] + b_hl[col], 0.f);
        }
    }
    __syncthreads();

    // ---- phase 6: g = relu(hg@W_gs + hl@W_ls + b_gs + b_ls)
    {
        int s = t >> 8, n = t & 255;
        float acc = b_gs[n] + b_ls[n];
        const float* hgp = s_hg[s];
        const float* hlp = s_hl[s];
        #pragma unroll 4
        for (int j = 0; j < HGN; ++j)
            acc += hgp[j] * W_gs[j * GN + n] + hlp[j] * W_ls[j * GN + n];
        out[(size_t)(b0 + s) * GN + n] = fmaxf(acc, 0.f);
    }
}

extern "C" void kernel_launch(void* const* d_in, const int* in_sizes, int n_in,
                              void* d_out, int out_size, void* d_ws, size_t ws_size,
                              hipStream_t stream) {
    const float* out_state = (const float*)d_in[0];
    const float* img       = (const float*)d_in[1];
    const float* W_loc     = (const float*)d_in[2];
    const float* b_loc     = (const float*)d_in[3];
    const float* W_hg      = (const float*)d_in[4];
    const float* b_hg      = (const float*)d_in[5];
    const float* W_hl      = (const float*)d_in[6];
    const float* b_hl      = (const float*)d_in[7];
    const float* W_gs      = (const float*)d_in[8];
    const float* b_gs      = (const float*)d_in[9];
    const float* W_ls      = (const float*)d_in[10];
    const float* b_ls      = (const float*)d_in[11];
    float* out = (float*)d_out;

    hipLaunchKernelGGL(fused_attn, dim3(NB/2), dim3(512), 0, stream,
                       out_state, img, W_loc, b_loc, W_hg, b_hg,
                       W_hl, b_hl, W_gs, b_gs, W_ls, b_ls, out);
}

// Round 3
// 21.193 us; speedup vs baseline: 2.0644x; 1.2534x over previous
//
#include <hip/hip_runtime.h>
#include <math.h>

// ---- problem constants ----
#define NB    512   // batch
#define STATE 512
#define IMS   224
#define TSB   768   // 3*16*16
#define HGN   128
#define GN    256
#define WPITCH 65   // 64 + 1 pad

// depth-1 (32->16) antialiased linear weights: taps at j = 2*o-1 + a
__device__ __forceinline__ void d1w(int o, float w[4]) {
    w[0] = 0.125f; w[1] = 0.375f; w[2] = 0.375f; w[3] = 0.125f;
    if (o == 0)  { w[0] = 0.f;      w[1] = 3.f/7.f; w[2] = 3.f/7.f; w[3] = 1.f/7.f; }
    if (o == 15) { w[0] = 1.f/7.f;  w[1] = 3.f/7.f; w[2] = 3.f/7.f; w[3] = 0.f; }
}
// depth-2 (64->16) weights: taps at j = 4*o-2 + a
__device__ __forceinline__ void d2w(int o, float w[8]) {
    const float s = 1.f/32.f;
    w[0]=1*s; w[1]=3*s; w[2]=5*s; w[3]=7*s; w[4]=7*s; w[5]=5*s; w[6]=3*s; w[7]=1*s;
    if (o == 0)  { const float t=1.f/28.f; w[0]=0.f; w[1]=0.f; w[2]=5*t; w[3]=7*t; w[4]=7*t; w[5]=5*t; w[6]=3*t; w[7]=1*t; }
    if (o == 15) { const float t=1.f/28.f; w[0]=1*t; w[1]=3*t; w[2]=5*t; w[3]=7*t; w[4]=7*t; w[5]=5*t; w[6]=0.f; w[7]=0.f; }
}

// Fully fused: loc -> glimpses -> hg -> hl -> g.  2 samples per block, 512 thr.
__global__ __launch_bounds__(512) void fused_attn(
    const float* __restrict__ out_state,  // [512][512]
    const float* __restrict__ img,        // [512][224][224]
    const float* __restrict__ W_loc, const float* __restrict__ b_loc,
    const float* __restrict__ W_hg,  const float* __restrict__ b_hg,
    const float* __restrict__ W_hl,  const float* __restrict__ b_hl,
    const float* __restrict__ W_gs,  const float* __restrict__ b_gs,
    const float* __restrict__ W_ls,  const float* __restrict__ b_ls,
    float* __restrict__ out)              // [512][256]
{
    __shared__ float win[2][64 * WPITCH];   // 33.3 KB
    __shared__ float gl[2][TSB];            // 6 KB
    __shared__ float s_hg[2][HGN];
    __shared__ float s_hl[2][HGN];
    __shared__ float part4[2][8][HGN];      // 8 KB  (phase-4 k-split partials)
    __shared__ float part6[2][4][GN];       // 8 KB  (phase-6 k-split partials)
    __shared__ float red[8][2];
    __shared__ float s_loc[2][2];
    __shared__ int   s_li[2][2];

    const int t  = threadIdx.x;
    const int b0 = blockIdx.x * 2;

    // ---- phase 1: loc = clip(output @ W_loc + b_loc)
    {
        int s = t >> 8, k = t & 255;
        const float* orow = out_state + (size_t)(b0 + s) * STATE;
        float x0 = orow[k], x1 = orow[k + 256];
        float a0 = x0 * W_loc[k*2]     + x1 * W_loc[(k+256)*2];
        float a1 = x0 * W_loc[k*2 + 1] + x1 * W_loc[(k+256)*2 + 1];
        for (int off = 32; off; off >>= 1) {
            a0 += __shfl_down(a0, off);
            a1 += __shfl_down(a1, off);
        }
        if ((t & 63) == 0) { red[t>>6][0] = a0; red[t>>6][1] = a1; }
    }
    __syncthreads();
    if ((t & 255) == 0) {
        int s = t >> 8;
        float l0 = red[4*s][0]+red[4*s+1][0]+red[4*s+2][0]+red[4*s+3][0] + b_loc[0];
        float l1 = red[4*s][1]+red[4*s+1][1]+red[4*s+2][1]+red[4*s+3][1] + b_loc[1];
        l0 = fminf(fmaxf(l0, -1.f), 1.f);
        l1 = fminf(fmaxf(l1, -1.f), 1.f);
        s_loc[s][0] = l0; s_loc[s][1] = l1;
        s_li[s][0] = (int)rintf((l0 + 1.f) * 0.5f * (float)IMS);
        s_li[s][1] = (int)rintf((l1 + 1.f) * 0.5f * (float)IMS);
    }
    __syncthreads();

    // ---- phase 2: 64x64 windows centered at loc, zero outside image
    #pragma unroll
    for (int i = 0; i < 16; ++i) {
        int idx = t + i * 512;
        int s = idx >> 12, rem = idx & 4095;
        int r = rem >> 6, c = rem & 63;
        int rr = s_li[s][0] - 32 + r, cc = s_li[s][1] - 32 + c;
        float v = 0.f;
        if ((unsigned)rr < (unsigned)IMS && (unsigned)cc < (unsigned)IMS)
            v = img[(size_t)(b0 + s) * IMS * IMS + rr * IMS + cc];
        win[s][r * WPITCH + c] = v;
    }
    __syncthreads();

    // ---- phase 3: 3-depth glimpses -> gl LDS
    {
        int s = t >> 8, p = t & 255, r = p >> 4, c = p & 15;
        const float* w = win[s];
        gl[s][p] = w[(24 + r) * WPITCH + (24 + c)];
        {
            float wr[4], wc[4];
            d1w(r, wr); d1w(c, wc);
            int jr0 = 16 + 2*r - 1, jc0 = 16 + 2*c - 1;
            float acc = 0.f;
            #pragma unroll
            for (int a = 0; a < 4; ++a) {
                float rowsum = 0.f;
                #pragma unroll
                for (int bb = 0; bb < 4; ++bb)
                    rowsum += wc[bb] * w[(jr0 + a) * WPITCH + (jc0 + bb)];
                acc += wr[a] * rowsum;
            }
            gl[s][256 + p] = acc;
        }
        {
            float wr[8], wc[8];
            d2w(r, wr); d2w(c, wc);
            int jr0 = 4*r - 2, jc0 = 4*c - 2;
            float acc = 0.f;
            #pragma unroll
            for (int a = 0; a < 8; ++a) {
                int jr = min(max(jr0 + a, 0), 63);
                float rowsum = 0.f;
                #pragma unroll
                for (int bb = 0; bb < 8; ++bb) {
                    int jc = min(max(jc0 + bb, 0), 63);
                    rowsum += wc[bb] * w[jr * WPITCH + jc];
                }
                acc += wr[a] * rowsum;
            }
            gl[s][512 + p] = acc;
        }
    }
    __syncthreads();

    // ---- phase 4: hg = relu(gl @ W_hg + b_hg)
    // thread (s, q, cg): s sample, q in 0..7 k-split (96 each), cg col-group (4 cols)
    {
        int s = t >> 8, u = t & 255, q = u >> 5, cg = u & 31;
        const float* gp = gl[s] + q * 96;
        const float* wp = W_hg + (size_t)(q * 96) * HGN + cg * 4;
        float4 acc = make_float4(0.f, 0.f, 0.f, 0.f);
        #pragma unroll 8
        for (int k = 0; k < 96; ++k) {
            float g = gp[k];
            float4 w4 = *(const float4*)(wp + (size_t)k * HGN);
            acc.x += g * w4.x; acc.y += g * w4.y;
            acc.z += g * w4.z; acc.w += g * w4.w;
        }
        *(float4*)&part4[s][q][cg * 4] = acc;
    }
    __syncthreads();
    // reduce partials (256 thr) + hl on the other 256 thr
    {
        int u = t & 255, s = u >> 7, col = u & 127;
        if (t < 256) {
            float a = b_hg[col];
            #pragma unroll
            for (int q = 0; q < 8; ++q) a += part4[s][q][col];
            s_hg[s][col] = fmaxf(a, 0.f);
        } else {
            float l0 = s_loc[s][0], l1 = s_loc[s][1];
            s_hl[s][col] = fmaxf(l0 * W_hl[col] + l1 * W_hl[HGN + col] + b_hl[col], 0.f);
        }
    }
    __syncthreads();

    // ---- phase 6: g = relu(hg@W_gs + hl@W_ls + b_gs + b_ls)
    // thread (s, q, cg): q in 0..3 (j-split, 32 each), cg col-group (4 cols of 256)
    {
        int s = t >> 8, u = t & 255, q = u >> 6, cg = u & 63;
        const float* hgp = s_hg[s] + q * 32;
        const float* hlp = s_hl[s] + q * 32;
        const float* wgs = W_gs + (size_t)(q * 32) * GN + cg * 4;
        const float* wls = W_ls + (size_t)(q * 32) * GN + cg * 4;
        float4 acc = make_float4(0.f, 0.f, 0.f, 0.f);
        #pragma unroll 8
        for (int j = 0; j < 32; ++j) {
            float hgj = hgp[j], hlj = hlp[j];
            float4 a4 = *(const float4*)(wgs + (size_t)j * GN);
            float4 b4 = *(const float4*)(wls + (size_t)j * GN);
            acc.x += hgj * a4.x + hlj * b4.x;
            acc.y += hgj * a4.y + hlj * b4.y;
            acc.z += hgj * a4.z + hlj * b4.z;
            acc.w += hgj * a4.w + hlj * b4.w;
        }
        *(float4*)&part6[s][q][cg * 4] = acc;
    }
    __syncthreads();
    {
        int s = t >> 8, n = t & 255;
        float a = b_gs[n] + b_ls[n];
        #pragma unroll
        for (int q = 0; q < 4; ++q) a += part6[s][q][n];
        out[(size_t)(b0 + s) * GN + n] = fmaxf(a, 0.f);
    }
}

extern "C" void kernel_launch(void* const* d_in, const int* in_sizes, int n_in,
                              void* d_out, int out_size, void* d_ws, size_t ws_size,
                              hipStream_t stream) {
    const float* out_state = (const float*)d_in[0];
    const float* img       = (const float*)d_in[1];
    const float* W_loc     = (const float*)d_in[2];
    const float* b_loc     = (const float*)d_in[3];
    const float* W_hg      = (const float*)d_in[4];
    const float* b_hg      = (const float*)d_in[5];
    const float* W_hl      = (const float*)d_in[6];
    const float* b_hl      = (const float*)d_in[7];
    const float* W_gs      = (const float*)d_in[8];
    const float* b_gs      = (const float*)d_in[9];
    const float* W_ls      = (const float*)d_in[10];
    const float* b_ls      = (const float*)d_in[11];
    float* out = (float*)d_out;

    hipLaunchKernelGGL(fused_attn, dim3(NB/2), dim3(512), 0, stream,
                       out_state, img, W_loc, b_loc, W_hg, b_hg,
                       W_hl, b_hl, W_gs, b_gs, W_ls, b_ls, out);
}

// Round 4
// 17.089 us; speedup vs baseline: 2.5602x; 1.2402x over previous
//
#include <hip/hip_runtime.h>
#include <math.h>

// ---- problem constants ----
#define NB    512   // batch
#define STATE 512
#define IMS   224
#define TSB   768   // 3*16*16
#define HGN   128
#define GN    256
#define WPITCH 65   // 64 + 1 pad

// depth-1 (32->16) antialiased linear weights: taps at j = 2*o-1 + a
__device__ __forceinline__ void d1w(int o, float w[4]) {
    w[0] = 0.125f; w[1] = 0.375f; w[2] = 0.375f; w[3] = 0.125f;
    if (o == 0)  { w[0] = 0.f;      w[1] = 3.f/7.f; w[2] = 3.f/7.f; w[3] = 1.f/7.f; }
    if (o == 15) { w[0] = 1.f/7.f;  w[1] = 3.f/7.f; w[2] = 3.f/7.f; w[3] = 0.f; }
}
// depth-2 (64->16) weights: taps at j = 4*o-2 + a
__device__ __forceinline__ void d2w(int o, float w[8]) {
    const float s = 1.f/32.f;
    w[0]=1*s; w[1]=3*s; w[2]=5*s; w[3]=7*s; w[4]=7*s; w[5]=5*s; w[6]=3*s; w[7]=1*s;
    if (o == 0)  { const float t=1.f/28.f; w[0]=0.f; w[1]=0.f; w[2]=5*t; w[3]=7*t; w[4]=7*t; w[5]=5*t; w[6]=3*t; w[7]=1*t; }
    if (o == 15) { const float t=1.f/28.f; w[0]=1*t; w[1]=3*t; w[2]=5*t; w[3]=7*t; w[4]=7*t; w[5]=5*t; w[6]=0.f; w[7]=0.f; }
}

// Fully fused: loc -> glimpses -> hg -> hl -> g.  2 samples per block, 512 thr.
// Weight loads in the GEMV phases are SHARED across the block's 2 samples.
__global__ __launch_bounds__(512) void fused_attn(
    const float* __restrict__ out_state,  // [512][512]
    const float* __restrict__ img,        // [512][224][224]
    const float* __restrict__ W_loc, const float* __restrict__ b_loc,
    const float* __restrict__ W_hg,  const float* __restrict__ b_hg,
    const float* __restrict__ W_hl,  const float* __restrict__ b_hl,
    const float* __restrict__ W_gs,  const float* __restrict__ b_gs,
    const float* __restrict__ W_ls,  const float* __restrict__ b_ls,
    float* __restrict__ out)              // [512][256]
{
    __shared__ float win[2][64 * WPITCH];   // 33.3 KB
    __shared__ float gl[2][TSB];            // 6 KB
    __shared__ float s_hg[2][HGN];
    __shared__ float s_hl[2][HGN];
    __shared__ float part4[2][16][HGN];     // 16 KB (phase-4 k-split partials)
    __shared__ float part6[2][8][GN];       // 16 KB (phase-6 j-split partials)
    __shared__ float red[8][2];
    __shared__ float s_loc[2][2];
    __shared__ int   s_li[2][2];

    const int t  = threadIdx.x;
    const int b0 = blockIdx.x * 2;

    // ---- phase 1: loc = clip(output @ W_loc + b_loc)
    {
        int s = t >> 8, k = t & 255;
        const float* orow = out_state + (size_t)(b0 + s) * STATE;
        float x0 = orow[k], x1 = orow[k + 256];
        float a0 = x0 * W_loc[k*2]     + x1 * W_loc[(k+256)*2];
        float a1 = x0 * W_loc[k*2 + 1] + x1 * W_loc[(k+256)*2 + 1];
        for (int off = 32; off; off >>= 1) {
            a0 += __shfl_down(a0, off);
            a1 += __shfl_down(a1, off);
        }
        if ((t & 63) == 0) { red[t>>6][0] = a0; red[t>>6][1] = a1; }
    }
    __syncthreads();
    if ((t & 255) == 0) {
        int s = t >> 8;
        float l0 = red[4*s][0]+red[4*s+1][0]+red[4*s+2][0]+red[4*s+3][0] + b_loc[0];
        float l1 = red[4*s][1]+red[4*s+1][1]+red[4*s+2][1]+red[4*s+3][1] + b_loc[1];
        l0 = fminf(fmaxf(l0, -1.f), 1.f);
        l1 = fminf(fmaxf(l1, -1.f), 1.f);
        s_loc[s][0] = l0; s_loc[s][1] = l1;
        s_li[s][0] = (int)rintf((l0 + 1.f) * 0.5f * (float)IMS);
        s_li[s][1] = (int)rintf((l1 + 1.f) * 0.5f * (float)IMS);
    }
    __syncthreads();

    // ---- phase 2: 64x64 windows centered at loc, zero outside image
    #pragma unroll
    for (int i = 0; i < 16; ++i) {
        int idx = t + i * 512;
        int s = idx >> 12, rem = idx & 4095;
        int r = rem >> 6, c = rem & 63;
        int rr = s_li[s][0] - 32 + r, cc = s_li[s][1] - 32 + c;
        float v = 0.f;
        if ((unsigned)rr < (unsigned)IMS && (unsigned)cc < (unsigned)IMS)
            v = img[(size_t)(b0 + s) * IMS * IMS + rr * IMS + cc];
        win[s][r * WPITCH + c] = v;
    }
    __syncthreads();

    // ---- phase 3: 3-depth glimpses -> gl LDS
    {
        int s = t >> 8, p = t & 255, r = p >> 4, c = p & 15;
        const float* w = win[s];
        gl[s][p] = w[(24 + r) * WPITCH + (24 + c)];
        {
            float wr[4], wc[4];
            d1w(r, wr); d1w(c, wc);
            int jr0 = 16 + 2*r - 1, jc0 = 16 + 2*c - 1;
            float acc = 0.f;
            #pragma unroll
            for (int a = 0; a < 4; ++a) {
                float rowsum = 0.f;
                #pragma unroll
                for (int bb = 0; bb < 4; ++bb)
                    rowsum += wc[bb] * w[(jr0 + a) * WPITCH + (jc0 + bb)];
                acc += wr[a] * rowsum;
            }
            gl[s][256 + p] = acc;
        }
        {
            float wr[8], wc[8];
            d2w(r, wr); d2w(c, wc);
            int jr0 = 4*r - 2, jc0 = 4*c - 2;
            float acc = 0.f;
            #pragma unroll
            for (int a = 0; a < 8; ++a) {
                int jr = min(max(jr0 + a, 0), 63);
                float rowsum = 0.f;
                #pragma unroll
                for (int bb = 0; bb < 8; ++bb) {
                    int jc = min(max(jc0 + bb, 0), 63);
                    rowsum += wc[bb] * w[jr * WPITCH + jc];
                }
                acc += wr[a] * rowsum;
            }
            gl[s][512 + p] = acc;
        }
    }
    __syncthreads();

    // ---- phase 4: hg = relu(gl @ W_hg + b_hg), weights shared across samples
    // thread: cg = t&31 (4 cols), q = t>>5 (0..15, 48 k each)
    {
        int cg = t & 31, q = t >> 5;
        const float* g0 = gl[0] + q * 48;
        const float* g1 = gl[1] + q * 48;
        const float* wp = W_hg + (size_t)(q * 48) * HGN + cg * 4;
        float4 acc0 = make_float4(0.f, 0.f, 0.f, 0.f);
        float4 acc1 = make_float4(0.f, 0.f, 0.f, 0.f);
        #pragma unroll 8
        for (int k = 0; k < 48; ++k) {
            float4 w4 = *(const float4*)(wp + (size_t)k * HGN);
            float a = g0[k], b = g1[k];
            acc0.x += a * w4.x; acc0.y += a * w4.y;
            acc0.z += a * w4.z; acc0.w += a * w4.w;
            acc1.x += b * w4.x; acc1.y += b * w4.y;
            acc1.z += b * w4.z; acc1.w += b * w4.w;
        }
        *(float4*)&part4[0][q][cg * 4] = acc0;
        *(float4*)&part4[1][q][cg * 4] = acc1;
    }
    __syncthreads();
    // reduce partials (256 thr) + hl on the other 256 thr
    {
        int u = t & 255, s = u >> 7, col = u & 127;
        if (t < 256) {
            float a = b_hg[col];
            #pragma unroll
            for (int q = 0; q < 16; ++q) a += part4[s][q][col];
            s_hg[s][col] = fmaxf(a, 0.f);
        } else {
            float l0 = s_loc[s][0], l1 = s_loc[s][1];
            s_hl[s][col] = fmaxf(l0 * W_hl[col] + l1 * W_hl[HGN + col] + b_hl[col], 0.f);
        }
    }
    __syncthreads();

    // ---- phase 6: g = relu(hg@W_gs + hl@W_ls + b_gs + b_ls), weights shared
    // thread: cg = t&63 (4 cols of 256), q = t>>6 (0..7, 16 j each)
    {
        int cg = t & 63, q = t >> 6;
        const float* hg0 = s_hg[0] + q * 16;
        const float* hg1 = s_hg[1] + q * 16;
        const float* hl0 = s_hl[0] + q * 16;
        const float* hl1 = s_hl[1] + q * 16;
        const float* wgs = W_gs + (size_t)(q * 16) * GN + cg * 4;
        const float* wls = W_ls + (size_t)(q * 16) * GN + cg * 4;
        float4 acc0 = make_float4(0.f, 0.f, 0.f, 0.f);
        float4 acc1 = make_float4(0.f, 0.f, 0.f, 0.f);
        #pragma unroll 8
        for (int j = 0; j < 16; ++j) {
            float4 a4 = *(const float4*)(wgs + (size_t)j * GN);
            float4 b4 = *(const float4*)(wls + (size_t)j * GN);
            float hga = hg0[j], hgb = hg1[j];
            float hla = hl0[j], hlb = hl1[j];
            acc0.x += hga * a4.x + hla * b4.x;
            acc0.y += hga * a4.y + hla * b4.y;
            acc0.z += hga * a4.z + hla * b4.z;
            acc0.w += hga * a4.w + hla * b4.w;
            acc1.x += hgb * a4.x + hlb * b4.x;
            acc1.y += hgb * a4.y + hlb * b4.y;
            acc1.z += hgb * a4.z + hlb * b4.z;
            acc1.w += hgb * a4.w + hlb * b4.w;
        }
        *(float4*)&part6[0][q][cg * 4] = acc0;
        *(float4*)&part6[1][q][cg * 4] = acc1;
    }
    __syncthreads();
    {
        int s = t >> 8, n = t & 255;
        float a = b_gs[n] + b_ls[n];
        #pragma unroll
        for (int q = 0; q < 8; ++q) a += part6[s][q][n];
        out[(size_t)(b0 + s) * GN + n] = fmaxf(a, 0.f);
    }
}

extern "C" void kernel_launch(void* const* d_in, const int* in_sizes, int n_in,
                              void* d_out, int out_size, void* d_ws, size_t ws_size,
                              hipStream_t stream) {
    const float* out_state = (const float*)d_in[0];
    const float* img       = (const float*)d_in[1];
    const float* W_loc     = (const float*)d_in[2];
    const float* b_loc     = (const float*)d_in[3];
    const float* W_hg      = (const float*)d_in[4];
    const float* b_hg      = (const float*)d_in[5];
    const float* W_hl      = (const float*)d_in[6];
    const float* b_hl      = (const float*)d_in[7];
    const float* W_gs      = (const float*)d_in[8];
    const float* b_gs      = (const float*)d_in[9];
    const float* W_ls      = (const float*)d_in[10];
    const float* b_ls      = (const float*)d_in[11];
    float* out = (float*)d_out;

    hipLaunchKernelGGL(fused_attn, dim3(NB/2), dim3(512), 0, stream,
                       out_state, img, W_loc, b_loc, W_hg, b_hg,
                       W_hl, b_hl, W_gs, b_gs, W_ls, b_ls, out);
}